// Round 3
// 217.314 us; speedup vs baseline: 1.0340x; 1.0340x over previous
//
#include <hip/hip_runtime.h>
#include <hip/hip_bf16.h>

#define BB 32
#define PP 1024
#define HID 512
#define NH 8
#define DD 64
#define MEM 64
#define RANK 64

typedef float f32x4 __attribute__((ext_vector_type(4)));

// Workspace layout (floats)
#define A_OFF   0          // [8][64]
#define M_OFF   512        // [17][17]
#define T_OFF   1024       // [32][8][64]
#define G_OFF   18432      // [32][16][1024]

// ---------------------------------------------------------------------------
// Kernel 1: precompute, coalesced. thread t -> (r = t>>4, dq = t&15).
// A[h][m]   = wk[h,:]·wmem[m,:]          (8 passes over h; m = r)
// WU[j][r]  = wu[r,:] slice · wv/bv row  (17 passes over j; WV stored ^T)
// M17[i][j] = Σ_r WU[i][r]*WV[j][r]
// ---------------------------------------------------------------------------
__global__ __launch_bounds__(1024) void k_precompute(
    const float* __restrict__ wk, const float* __restrict__ wmem,
    const float* __restrict__ wv, const float* __restrict__ bv,
    const float* __restrict__ wu, const float* __restrict__ bu,
    const float* __restrict__ wv2, const float* __restrict__ bv2,
    float* __restrict__ A, float* __restrict__ M17) {
  __shared__ float WU[17 * 64];    // [i][r]
  __shared__ float WVt[64 * 17];   // [r][j]  (transposed: conflict-free M17)
  const int t = threadIdx.x;
  const int r = t >> 4;    // 0..63
  const int dq = t & 15;   // 0..15 -> d = dq*4 .. dq*4+3

  // ---- A: coalesced wmem float4 loads, wk broadcast, 4-step group reduce
  const float4 wm4 = *(const float4*)&wmem[r * DD + dq * 4];
  for (int h = 0; h < NH; ++h) {
    const float4 wk4 = *(const float4*)&wk[h * DD + dq * 4];
    float s = wm4.x * wk4.x + wm4.y * wk4.y + wm4.z * wk4.z + wm4.w * wk4.w;
    s += __shfl_xor(s, 1); s += __shfl_xor(s, 2);
    s += __shfl_xor(s, 4); s += __shfl_xor(s, 8);
    if (dq == 0) A[h * MEM + r] = s;
  }

  // ---- WU / WV rows (j = 0..16). wu/wv2 reads: 16 lanes cover 256 B of
  // row r contiguously -> fully coalesced.
  for (int j = 0; j < 17; ++j) {
    float su, sv;
    if (j < 16) {
      const int hh = j & 7;
      const float4 w4 = (j < 8) ? *(const float4*)&wv[hh * DD + dq * 4]
                                : *(const float4*)&bv[hh * DD + dq * 4];
      const float4 u4 = *(const float4*)&wu[r * HID + hh * DD + dq * 4];
      const float4 v4 = *(const float4*)&wv2[r * HID + hh * DD + dq * 4];
      su = u4.x * w4.x + u4.y * w4.y + u4.z * w4.z + u4.w * w4.w;
      sv = v4.x * w4.x + v4.y * w4.y + v4.z * w4.z + v4.w * w4.w;
    } else {
      su = (dq == 0) ? bu[r] : 0.f;
      sv = (dq == 0) ? bv2[r] : 0.f;
    }
    su += __shfl_xor(su, 1); su += __shfl_xor(su, 2);
    su += __shfl_xor(su, 4); su += __shfl_xor(su, 8);
    sv += __shfl_xor(sv, 1); sv += __shfl_xor(sv, 2);
    sv += __shfl_xor(sv, 4); sv += __shfl_xor(sv, 8);
    if (dq == 0) {
      WU[j * 64 + r] = su;
      WVt[r * 17 + j] = sv;
    }
  }
  __syncthreads();

  // ---- M17: WU broadcast across j-lanes, WVt consecutive -> conflict-free
  if (t < 17 * 17) {
    const int ii = t / 17, jj = t - ii * 17;
    float s = 0.f;
    for (int rr = 0; rr < 64; ++rr) s += WU[ii * 64 + rr] * WVt[rr * 17 + jj];
    M17[t] = s;
  }
}

// ---------------------------------------------------------------------------
// Kernel 2: T[b,h,m] = softmax_p(x[b,p]*A[h,m]) weighted mean of x.
// One wave per (b,h,m) task; 16384 tasks; 4 waves per block. (unchanged)
// ---------------------------------------------------------------------------
__global__ __launch_bounds__(256) void k_memsoftmax(
    const float* __restrict__ x, const float* __restrict__ A,
    float* __restrict__ T) {
  const int wid = blockIdx.x * 4 + (threadIdx.x >> 6);   // [0, 16384)
  const int lane = threadIdx.x & 63;
  const int b = wid >> 9;
  const int hm = wid & 511;               // h*64+m
  const float a = A[hm];
  const float* xr = x + b * PP;

  float xs[16];
  float mx = -INFINITY;
#pragma unroll
  for (int k = 0; k < 16; ++k) {
    xs[k] = xr[lane + k * 64];
    mx = fmaxf(mx, xs[k] * a);
  }
#pragma unroll
  for (int off = 32; off >= 1; off >>= 1) mx = fmaxf(mx, __shfl_xor(mx, off));

  float s = 0.f, sx = 0.f;
#pragma unroll
  for (int k = 0; k < 16; ++k) {
    const float e = __expf(xs[k] * a - mx);
    s += e;
    sx += e * xs[k];
  }
#pragma unroll
  for (int off = 32; off >= 1; off >>= 1) {
    s += __shfl_xor(s, off);
    sx += __shfl_xor(sx, off);
  }
  if (lane == 0) T[wid] = sx / s;
}

// ---------------------------------------------------------------------------
// Kernel 3 (was k4+k_tsums): per (b,h,p): a1 = Σ_d φ(x*wq+bq)*wv,
// a0 = Σ_d φ(...)*bv. S1/S2 computed in-block by wave 0 (shuffle reduce).
// c1 = a1*S2 + a0*S1 -> G[b][h][p];  c2 = a1*S1 + a0*MEM -> G[b][8+h][p].
// ---------------------------------------------------------------------------
__global__ __launch_bounds__(256) void k_features(
    const float* __restrict__ x, const float* __restrict__ wq,
    const float* __restrict__ bq, const float* __restrict__ wv,
    const float* __restrict__ bv, const float* __restrict__ T,
    float* __restrict__ G) {
  __shared__ float sS1, sS2;
  const int idx0 = blockIdx.x * 256;
  const int b = idx0 >> 13;
  const int h = (idx0 >> 10) & 7;
  const int p = (idx0 & 1023) + threadIdx.x;
  const int t = threadIdx.x;

  if (t < 64) {                      // wave 0: S1/S2 from T row
    const float v = T[(b * NH + h) * MEM + t];
    float s1 = v, s2 = v * v;
#pragma unroll
    for (int off = 32; off >= 1; off >>= 1) {
      s1 += __shfl_xor(s1, off);
      s2 += __shfl_xor(s2, off);
    }
    if (t == 0) { sS1 = s1; sS2 = s2; }
  }

  const float xv = x[b * PP + p];
  float a1 = 0.f, a0 = 0.f;
#pragma unroll 8
  for (int d = 0; d < DD; ++d) {
    const float q = xv * wq[h * DD + d] + bq[h * DD + d];
    const float ph = (q > 0.f) ? (q + 1.f) : __expf(q);
    a1 += ph * wv[h * DD + d];
    a0 += ph * bv[h * DD + d];
  }
  __syncthreads();
  const float s1 = sS1, s2 = sS2;
  const float c1 = a1 * s2 + a0 * s1;
  const float c2 = a1 * s1 + a0 * (float)MEM;
  G[(b * 16 + h) * PP + p] = c1;
  G[(b * 16 + 8 + h) * PP + p] = c2;
}

// ---------------------------------------------------------------------------
// Kernel 4 (was k_fmap+k_coeffs): 128x128 tile per block, 256 threads,
// thread computes 8p x 8q. F computed in-LDS from Gp and M17 (rank-17 fold).
// out[b,p,q] = F[16][p] + Σ_{j<16} F[j][p]*G[j][q]. NT stores for out.
// ---------------------------------------------------------------------------
__global__ __launch_bounds__(256) void k_coeffs(
    const float* __restrict__ G, const float* __restrict__ M17,
    float* __restrict__ out) {
  __shared__ float Ml[17 * 17];
  __shared__ float Gp[16 * 128];
  __shared__ float Gq[16 * 128];
  __shared__ float Fl[17 * 128];
  const int b = blockIdx.z;
  const int p0 = blockIdx.y * 128;
  const int q0 = blockIdx.x * 128;
  const int t = threadIdx.x;
  const float* Gg = G + (size_t)b * 16 * PP;

  for (int i = t; i < 17 * 17; i += 256) Ml[i] = M17[i];
  for (int i = t; i < 16 * 128; i += 256) {
    const int row = i >> 7, col = i & 127;
    Gp[i] = Gg[row * PP + p0 + col];
    Gq[i] = Gg[row * PP + q0 + col];
  }
  __syncthreads();

  // Fl[j][pp] = M[16][j] + Σ_i Gp[i][pp]*M[i][j]  (j uniform per wave,
  // pp consecutive -> conflict-free; Ml broadcast)
  for (int i = t; i < 17 * 128; i += 256) {
    const int j = i >> 7, pp = i & 127;
    float f = Ml[16 * 17 + j];
#pragma unroll
    for (int ii = 0; ii < 16; ++ii) f += Gp[ii * 128 + pp] * Ml[ii * 17 + j];
    Fl[i] = f;
  }
  __syncthreads();

  const int pr = t >> 4;   // 0..15 -> rows pr*8 .. pr*8+7
  const int qv = t & 15;   // 0..15 -> cols qv*8 .. qv*8+7

  float acc[8][8];
#pragma unroll
  for (int r = 0; r < 8; ++r) {
    const float f16 = Fl[16 * 128 + pr * 8 + r];
#pragma unroll
    for (int c = 0; c < 8; ++c) acc[r][c] = f16;
  }

#pragma unroll
  for (int j = 0; j < 16; ++j) {
    const float4 fj0 = *(const float4*)&Fl[j * 128 + pr * 8];
    const float4 fj1 = *(const float4*)&Fl[j * 128 + pr * 8 + 4];
    const float4 gj0 = *(const float4*)&Gq[j * 128 + qv * 8];
    const float4 gj1 = *(const float4*)&Gq[j * 128 + qv * 8 + 4];
    const float fr[8] = {fj0.x, fj0.y, fj0.z, fj0.w, fj1.x, fj1.y, fj1.z, fj1.w};
    const float gc[8] = {gj0.x, gj0.y, gj0.z, gj0.w, gj1.x, gj1.y, gj1.z, gj1.w};
#pragma unroll
    for (int r = 0; r < 8; ++r) {
#pragma unroll
      for (int c = 0; c < 8; ++c) acc[r][c] += fr[r] * gc[c];
    }
  }

  const size_t base = ((size_t)b * PP + p0 + pr * 8) * PP + q0 + qv * 8;
#pragma unroll
  for (int r = 0; r < 8; ++r) {
    const f32x4 v0 = {acc[r][0], acc[r][1], acc[r][2], acc[r][3]};
    const f32x4 v1 = {acc[r][4], acc[r][5], acc[r][6], acc[r][7]};
    __builtin_nontemporal_store(v0, (f32x4*)&out[base + (size_t)r * PP]);
    __builtin_nontemporal_store(v1, (f32x4*)&out[base + (size_t)r * PP + 4]);
  }
}

extern "C" void kernel_launch(void* const* d_in, const int* in_sizes, int n_in,
                              void* d_out, int out_size, void* d_ws, size_t ws_size,
                              hipStream_t stream) {
  const float* x    = (const float*)d_in[0];
  const float* wq   = (const float*)d_in[1];
  const float* bq   = (const float*)d_in[2];
  const float* wk   = (const float*)d_in[3];
  const float* bk   = (const float*)d_in[4];  (void)bk;  // drops out of softmax
  const float* wv   = (const float*)d_in[5];
  const float* bv   = (const float*)d_in[6];
  const float* wmem = (const float*)d_in[7];
  const float* wu   = (const float*)d_in[8];
  const float* bu   = (const float*)d_in[9];
  const float* wv2  = (const float*)d_in[10];
  const float* bv2  = (const float*)d_in[11];

  float* ws = (float*)d_ws;
  float* A   = ws + A_OFF;
  float* M17 = ws + M_OFF;
  float* T   = ws + T_OFF;
  float* G   = ws + G_OFF;
  float* out = (float*)d_out;

  k_precompute<<<1, 1024, 0, stream>>>(wk, wmem, wv, bv, wu, bu, wv2, bv2, A, M17);
  k_memsoftmax<<<4096, 256, 0, stream>>>(x, A, T);
  k_features<<<1024, 256, 0, stream>>>(x, wq, bq, wv, bv, T, G);
  k_coeffs<<<dim3(8, 8, 32), 256, 0, stream>>>(G, M17, out);
}

// Round 4
// 210.731 us; speedup vs baseline: 1.0663x; 1.0312x over previous
//
#include <hip/hip_runtime.h>
#include <hip/hip_bf16.h>

#define BB 32
#define PP 1024
#define HID 512
#define NH 8
#define DD 64
#define MEM 64
#define RANK 64

typedef float f32x4 __attribute__((ext_vector_type(4)));

// Workspace layout (floats)
#define M_OFF   512        // [17][17]
#define G_OFF   18432      // [32][16][1024]

// ---------------------------------------------------------------------------
// Kernel 1 (fused precompute + memsoftmax + tsums + features).
// Blocks 0..255: one (b,h) per block, 1024 threads (16 waves).
//   wave w handles m = 4w..4w+3: A[h][m] inline (64-dot + butterfly),
//   softmax_p(x*A) weighted mean -> Tl[m] (LDS).
//   Then S1/S2 block-reduce, then feature pass (p = tid) -> G.
// Block 256: M17[i][j] = Σ_r WU[i][r]*WV[j][r] (rank-17 fold matrix).
// ---------------------------------------------------------------------------
__global__ __launch_bounds__(1024) void k_fused(
    const float* __restrict__ x, const float* __restrict__ wq,
    const float* __restrict__ bq, const float* __restrict__ wk,
    const float* __restrict__ wv, const float* __restrict__ bv,
    const float* __restrict__ wmem, const float* __restrict__ wu,
    const float* __restrict__ bu, const float* __restrict__ wv2,
    const float* __restrict__ bv2, float* __restrict__ G,
    float* __restrict__ M17) {
  const int t = threadIdx.x;

  if (blockIdx.x == 256) {
    // ---- M17 precompute (one block). thread t -> (r = t>>4, dq = t&15).
    __shared__ float WU[17 * 64];    // [i][r]
    __shared__ float WVt[64 * 17];   // [r][j]
    const int r = t >> 4;
    const int dq = t & 15;
    for (int j = 0; j < 17; ++j) {
      float su, sv;
      if (j < 16) {
        const int hh = j & 7;
        const float4 w4 = (j < 8) ? *(const float4*)&wv[hh * DD + dq * 4]
                                  : *(const float4*)&bv[hh * DD + dq * 4];
        const float4 u4 = *(const float4*)&wu[r * HID + hh * DD + dq * 4];
        const float4 v4 = *(const float4*)&wv2[r * HID + hh * DD + dq * 4];
        su = u4.x * w4.x + u4.y * w4.y + u4.z * w4.z + u4.w * w4.w;
        sv = v4.x * w4.x + v4.y * w4.y + v4.z * w4.z + v4.w * w4.w;
      } else {
        su = (dq == 0) ? bu[r] : 0.f;
        sv = (dq == 0) ? bv2[r] : 0.f;
      }
      su += __shfl_xor(su, 1); su += __shfl_xor(su, 2);
      su += __shfl_xor(su, 4); su += __shfl_xor(su, 8);
      sv += __shfl_xor(sv, 1); sv += __shfl_xor(sv, 2);
      sv += __shfl_xor(sv, 4); sv += __shfl_xor(sv, 8);
      if (dq == 0) {
        WU[j * 64 + r] = su;
        WVt[r * 17 + j] = sv;
      }
    }
    __syncthreads();
    if (t < 17 * 17) {
      const int ii = t / 17, jj = t - ii * 17;
      float s = 0.f;
      for (int rr = 0; rr < 64; ++rr) s += WU[ii * 64 + rr] * WVt[rr * 17 + jj];
      M17[t] = s;
    }
    return;
  }

  // ---- blocks 0..255: b,h fixed per block
  __shared__ float Tl[MEM];
  __shared__ float sS1, sS2;
  const int b = blockIdx.x >> 3;
  const int h = blockIdx.x & 7;
  const int w = t >> 6;      // wave 0..15
  const int lane = t & 63;
  const float* xr = x + b * PP;

  // feature-phase input (load early, no barrier dependency)
  const float xv = xr[t];

  // per-lane x slice for the softmax phase
  float xs[16];
#pragma unroll
  for (int k = 0; k < 16; ++k) xs[k] = xr[lane + k * 64];

  // wave w: m = 4w .. 4w+3
  for (int mi = 0; mi < 4; ++mi) {
    const int m = w * 4 + mi;
    // A[h][m] = wk[h,:]·wmem[m,:]  (lane-parallel 64-dot, full butterfly)
    float a = wk[h * DD + lane] * wmem[m * DD + lane];
#pragma unroll
    for (int off = 32; off >= 1; off >>= 1) a += __shfl_xor(a, off);

    float mx = -INFINITY;
#pragma unroll
    for (int k = 0; k < 16; ++k) mx = fmaxf(mx, xs[k] * a);
#pragma unroll
    for (int off = 32; off >= 1; off >>= 1) mx = fmaxf(mx, __shfl_xor(mx, off));

    float s = 0.f, sx = 0.f;
#pragma unroll
    for (int k = 0; k < 16; ++k) {
      const float e = __expf(xs[k] * a - mx);
      s += e;
      sx += e * xs[k];
    }
#pragma unroll
    for (int off = 32; off >= 1; off >>= 1) {
      s += __shfl_xor(s, off);
      sx += __shfl_xor(sx, off);
    }
    if (lane == 0) Tl[m] = sx / s;
  }
  __syncthreads();

  // S1/S2 from Tl (wave 0)
  if (t < 64) {
    const float v = Tl[t];
    float s1 = v, s2 = v * v;
#pragma unroll
    for (int off = 32; off >= 1; off >>= 1) {
      s1 += __shfl_xor(s1, off);
      s2 += __shfl_xor(s2, off);
    }
    if (t == 0) { sS1 = s1; sS2 = s2; }
  }
  __syncthreads();

  // feature pass: p = t
  float a1 = 0.f, a0 = 0.f;
#pragma unroll 8
  for (int d = 0; d < DD; ++d) {
    const float q = xv * wq[h * DD + d] + bq[h * DD + d];
    const float ph = (q > 0.f) ? (q + 1.f) : __expf(q);
    a1 += ph * wv[h * DD + d];
    a0 += ph * bv[h * DD + d];
  }
  const float s1 = sS1, s2 = sS2;
  const float c1 = a1 * s2 + a0 * s1;
  const float c2 = a1 * s1 + a0 * (float)MEM;
  G[(b * 16 + h) * PP + t] = c1;
  G[(b * 16 + 8 + h) * PP + t] = c2;
}

// ---------------------------------------------------------------------------
// Kernel 2: 128x128 tile per block, 256 threads, thread computes 8p x 8q.
// F computed in-LDS from Gp and M17 (rank-17 fold). NT stores for out.
// out[b,p,q] = F[16][p] + Σ_{j<16} F[j][p]*G[j][q].
// ---------------------------------------------------------------------------
__global__ __launch_bounds__(256) void k_coeffs(
    const float* __restrict__ G, const float* __restrict__ M17,
    float* __restrict__ out) {
  __shared__ float Ml[17 * 17];
  __shared__ float Gp[16 * 128];
  __shared__ float Gq[16 * 128];
  __shared__ float Fl[17 * 128];
  const int b = blockIdx.z;
  const int p0 = blockIdx.y * 128;
  const int q0 = blockIdx.x * 128;
  const int t = threadIdx.x;
  const float* Gg = G + (size_t)b * 16 * PP;

  for (int i = t; i < 17 * 17; i += 256) Ml[i] = M17[i];
  for (int i = t; i < 16 * 128; i += 256) {
    const int row = i >> 7, col = i & 127;
    Gp[i] = Gg[row * PP + p0 + col];
    Gq[i] = Gg[row * PP + q0 + col];
  }
  __syncthreads();

  for (int i = t; i < 17 * 128; i += 256) {
    const int j = i >> 7, pp = i & 127;
    float f = Ml[16 * 17 + j];
#pragma unroll
    for (int ii = 0; ii < 16; ++ii) f += Gp[ii * 128 + pp] * Ml[ii * 17 + j];
    Fl[i] = f;
  }
  __syncthreads();

  const int pr = t >> 4;   // 0..15 -> rows pr*8 .. pr*8+7
  const int qv = t & 15;   // 0..15 -> cols qv*8 .. qv*8+7

  float acc[8][8];
#pragma unroll
  for (int r = 0; r < 8; ++r) {
    const float f16 = Fl[16 * 128 + pr * 8 + r];
#pragma unroll
    for (int c = 0; c < 8; ++c) acc[r][c] = f16;
  }

#pragma unroll
  for (int j = 0; j < 16; ++j) {
    const float4 fj0 = *(const float4*)&Fl[j * 128 + pr * 8];
    const float4 fj1 = *(const float4*)&Fl[j * 128 + pr * 8 + 4];
    const float4 gj0 = *(const float4*)&Gq[j * 128 + qv * 8];
    const float4 gj1 = *(const float4*)&Gq[j * 128 + qv * 8 + 4];
    const float fr[8] = {fj0.x, fj0.y, fj0.z, fj0.w, fj1.x, fj1.y, fj1.z, fj1.w};
    const float gc[8] = {gj0.x, gj0.y, gj0.z, gj0.w, gj1.x, gj1.y, gj1.z, gj1.w};
#pragma unroll
    for (int r = 0; r < 8; ++r) {
#pragma unroll
      for (int c = 0; c < 8; ++c) acc[r][c] += fr[r] * gc[c];
    }
  }

  const size_t base = ((size_t)b * PP + p0 + pr * 8) * PP + q0 + qv * 8;
#pragma unroll
  for (int r = 0; r < 8; ++r) {
    const f32x4 v0 = {acc[r][0], acc[r][1], acc[r][2], acc[r][3]};
    const f32x4 v1 = {acc[r][4], acc[r][5], acc[r][6], acc[r][7]};
    __builtin_nontemporal_store(v0, (f32x4*)&out[base + (size_t)r * PP]);
    __builtin_nontemporal_store(v1, (f32x4*)&out[base + (size_t)r * PP + 4]);
  }
}

extern "C" void kernel_launch(void* const* d_in, const int* in_sizes, int n_in,
                              void* d_out, int out_size, void* d_ws, size_t ws_size,
                              hipStream_t stream) {
  const float* x    = (const float*)d_in[0];
  const float* wq   = (const float*)d_in[1];
  const float* bq   = (const float*)d_in[2];
  const float* wk   = (const float*)d_in[3];
  const float* bk   = (const float*)d_in[4];  (void)bk;  // drops out of softmax
  const float* wv   = (const float*)d_in[5];
  const float* bv   = (const float*)d_in[6];
  const float* wmem = (const float*)d_in[7];
  const float* wu   = (const float*)d_in[8];
  const float* bu   = (const float*)d_in[9];
  const float* wv2  = (const float*)d_in[10];
  const float* bv2  = (const float*)d_in[11];

  float* ws = (float*)d_ws;
  float* M17 = ws + M_OFF;
  float* G   = ws + G_OFF;
  float* out = (float*)d_out;

  k_fused<<<257, 1024, 0, stream>>>(x, wq, bq, wk, wv, bv, wmem, wu, bu,
                                    wv2, bv2, G, M17);
  k_coeffs<<<dim3(8, 8, 32), 256, 0, stream>>>(G, M17, out);
}